// Round 9
// baseline (518.194 us; speedup 1.0000x reference)
//
#include <hip/hip_runtime.h>

#define T_N 1024
#define H_N 128
#define CH   64
#define NCH (T_N / CH)     // 16
#define WPAD 136           // shorts per row of bf16 weight tiles
#define PPAD 68            // floats per row of pT
#define XGRP 1040          // bytes per 2-row DMA group (1024 data + 16 pad)
#define XBUF_BYTES (32 * XGRP)

typedef __attribute__((ext_vector_type(8))) short bf16x8;
typedef __attribute__((ext_vector_type(4))) float f32x4;

// LDS-only barrier: no vmcnt drain, x-DMA stays in flight
#define BAR_LGKM() asm volatile("s_waitcnt lgkmcnt(0)\n\ts_barrier" ::: "memory")

__device__ __forceinline__ short f2bf_rne(float f) {
    union { float f; unsigned int i; } v; v.f = f;
    unsigned int r = v.i + 0x7FFFu + ((v.i >> 16) & 1u);
    return (short)(r >> 16);
}
__device__ __forceinline__ float tanh_fast(float x) {
    return 1.0f - 2.0f / (__expf(2.0f * x) + 1.0f);
}
// state-slot permutation: col c=[wv:2][u:1][l:4] -> slot [wv:2][l:4][u:1]
__device__ __forceinline__ int slotof(int c) {
    return (c & 0x60) | ((c & 0x0F) << 1) | ((c >> 4) & 1);
}

// One block per batch row; 4 waves split the per-step matvec by column (nt pairs).
__global__ __launch_bounds__(256, 1) void k_fused(const float* __restrict__ x,
                                                  const float* __restrict__ w,
                                                  const float* __restrict__ wst,
                                                  const float* __restrict__ bias,
                                                  float* __restrict__ out) {
    __shared__ __align__(16) short wT[H_N * WPAD];      // input-proj w, bf16 [n][k]
    __shared__ __align__(16) float pT[H_N * PPAD];      // proj chunk [h][t]; wsT staging at startup
    __shared__ __align__(16) char  xbuf[2][XBUF_BYTES]; // fp32 x chunk, DMA double buffer
    __shared__ __align__(16) short sst[2][H_N];         // slot-permuted state double buffer, bf16

    const int tid  = threadIdx.x;
    const int wv   = tid >> 6;       // wave: owns cols 32wv+l, 32wv+16+l (nt = 2wv, 2wv+1)
    const int lane = tid & 63;
    const int l = lane & 15;
    const int q = lane >> 4;
    const int r = blockIdx.x;
    const float* xrow = x + (size_t)r * T_N * H_N;
    const f32x4 zero4 = (f32x4){0.f, 0.f, 0.f, 0.f};

    // ---- DMA chunk 0 (drained by the prologue's first __syncthreads) ----
    {
        const char* gsrc = (const char*)xrow;
        #pragma unroll
        for (int kk = 0; kk < 8; ++kk) {
            int k = wv * 8 + kk;
            __builtin_amdgcn_global_load_lds(
                (const __attribute__((address_space(1))) void*)(gsrc + k * 1024 + lane * 16),
                (__attribute__((address_space(3))) void*)(&xbuf[0][k * XGRP]),
                16, 0, 0);
        }
    }

    // ---- stage wst -> bf16 [n][k_slot] through pT's memory (Δb: slot-permuted k) ----
    short* wsT = reinterpret_cast<short*>(pT);
    for (int e = tid * 4; e < H_N * H_N; e += 1024) {
        int k = e >> 7, n = e & 127, s = slotof(k);
        float4 a4 = *reinterpret_cast<const float4*>(wst + e);
        wsT[(n + 0) * WPAD + s] = f2bf_rne(a4.x);
        wsT[(n + 1) * WPAD + s] = f2bf_rne(a4.y);
        wsT[(n + 2) * WPAD + s] = f2bf_rne(a4.z);
        wsT[(n + 3) * WPAD + s] = f2bf_rne(a4.w);
    }
    __syncthreads();

    bf16x8 wf[2][4];   // state-W B-frags for this wave's nt pair
    #pragma unroll
    for (int b = 0; b < 2; ++b)
        #pragma unroll
        for (int ks = 0; ks < 4; ++ks)
            wf[b][ks] = *reinterpret_cast<const bf16x8*>(
                &wsT[(16 * (2 * wv + b) + l) * WPAD + ks * 32 + q * 8]);
    __syncthreads();

    // ---- input-proj weights -> bf16 [n][k] LDS (natural k) ----
    for (int e = tid * 4; e < H_N * H_N; e += 1024) {
        int k = e >> 7, n = e & 127;
        float4 a4 = *reinterpret_cast<const float4*>(w + e);
        wT[(n + 0) * WPAD + k] = f2bf_rne(a4.x);
        wT[(n + 1) * WPAD + k] = f2bf_rne(a4.y);
        wT[(n + 2) * WPAD + k] = f2bf_rne(a4.z);
        wT[(n + 3) * WPAD + k] = f2bf_rne(a4.w);
    }

    float bv[8];
    #pragma unroll
    for (int nt = 0; nt < 8; ++nt) bv[nt] = bias[nt * 16 + l];

    int par = 0;
    float y0 = 0.f, y1 = 0.f;
    const int row0 = (32 * wv + l) * PPAD;
    const int row1 = (32 * wv + 16 + l) * PPAD;

    #pragma unroll 1
    for (int c = 0; c < NCH; ++c) {
        // full drain: xbuf[c&1] DMA (issued a whole chunk ago) complete; pT free
        __syncthreads();

        // ---- chunk GEMM: wave wv computes proj rows [c*64+16wv .. +15] ----
        {
            const char* xb = xbuf[c & 1];
            int row = wv * 16 + l;
            const float* pr = reinterpret_cast<const float*>(
                xb + (row >> 1) * XGRP + (row & 1) * 512);
            bf16x8 ax[4];
            #pragma unroll
            for (int ks = 0; ks < 4; ++ks) {
                float4 u0 = *reinterpret_cast<const float4*>(pr + ks * 32 + q * 8);
                float4 u1 = *reinterpret_cast<const float4*>(pr + ks * 32 + q * 8 + 4);
                bf16x8 f;
                f[0] = f2bf_rne(u0.x); f[1] = f2bf_rne(u0.y);
                f[2] = f2bf_rne(u0.z); f[3] = f2bf_rne(u0.w);
                f[4] = f2bf_rne(u1.x); f[5] = f2bf_rne(u1.y);
                f[6] = f2bf_rne(u1.z); f[7] = f2bf_rne(u1.w);
                ax[ks] = f;
            }
            #pragma unroll
            for (int nt = 0; nt < 8; ++nt) {
                f32x4 acc;
                #pragma unroll
                for (int ks = 0; ks < 4; ++ks) {
                    bf16x8 bw = *reinterpret_cast<const bf16x8*>(
                        &wT[(nt * 16 + l) * WPAD + ks * 32 + q * 8]);
                    acc = __builtin_amdgcn_mfma_f32_16x16x32_bf16(
                        ax[ks], bw, ks == 0 ? zero4 : acc, 0, 0, 0);
                }
                f32x4 o = (f32x4){acc[0] + bv[nt], acc[1] + bv[nt],
                                  acc[2] + bv[nt], acc[3] + bv[nt]};
                *reinterpret_cast<f32x4*>(&pT[(nt * 16 + l) * PPAD + wv * 16 + q * 4]) = o;
            }
        }

        // ---- DMA chunk c+1 (R6 placement; never drained by step barriers now) ----
        if (c + 1 < NCH) {
            const char* gsrc = (const char*)(xrow + (size_t)(c + 1) * CH * H_N);
            char* ldst = &xbuf[(c + 1) & 1][0];
            #pragma unroll
            for (int kk = 0; kk < 8; ++kk) {
                int k = wv * 8 + kk;
                __builtin_amdgcn_global_load_lds(
                    (const __attribute__((address_space(1))) void*)(gsrc + k * 1024 + lane * 16),
                    (__attribute__((address_space(3))) void*)(&xbuf[(c + 1) & 1][k * XGRP]),
                    16, 0, 0);
            }
            (void)ldst;
        }

        BAR_LGKM();   // Δa: pT ready — lgkm-only, DMA stays in flight

        int tstart = 0;
        if (c == 0) {
            if (tid < 128)   // wave-uniform (waves 0,1); slot-permuted init
                sst[0][slotof(tid)] = f2bf_rne(tanh_fast(pT[tid * PPAD + 0]));
            BAR_LGKM();
            tstart = 1;
            par = 0;
        }

        // p prefetch for first step of the chunk (R6 style: per-step scalar)
        float p0 = pT[row0 + tstart];
        float p1 = pT[row1 + tstart];

        #pragma unroll 1
        for (int t = tstart; t < CH; ++t) {
            bf16x8 a[4];
            #pragma unroll
            for (int ks = 0; ks < 4; ++ks)
                a[ks] = *reinterpret_cast<const bf16x8*>(&sst[par][ks * 32 + q * 8]);

            // Δc: p enters through the C operand (reg 0 = row 4q = the row we read)
            f32x4 c0 = (f32x4){p0, 0.f, 0.f, 0.f};
            f32x4 c1 = (f32x4){p1, 0.f, 0.f, 0.f};
            f32x4 acc[8];
            #pragma unroll
            for (int ks = 0; ks < 4; ++ks) {
                acc[ks]     = __builtin_amdgcn_mfma_f32_16x16x32_bf16(
                                  a[ks], wf[0][ks], ks == 0 ? c0 : zero4, 0, 0, 0);
                acc[4 + ks] = __builtin_amdgcn_mfma_f32_16x16x32_bf16(
                                  a[ks], wf[1][ks], ks == 0 ? c1 : zero4, 0, 0, 0);
            }

            int tn = (t + 1 < CH) ? t + 1 : t;
            float np0 = pT[row0 + tn];
            float np1 = pT[row1 + tn];

            float z0 = (acc[0][0] + acc[1][0]) + (acc[2][0] + acc[3][0]);
            float z1 = (acc[4][0] + acc[5][0]) + (acc[6][0] + acc[7][0]);
            y0 = tanh_fast(z0);
            y1 = tanh_fast(z1);

            if (q == 0) {   // Δb: 16 lanes, 16 distinct banks, one packed b32 write
                unsigned int pk = (unsigned int)(unsigned short)f2bf_rne(y0)
                                | ((unsigned int)(unsigned short)f2bf_rne(y1) << 16);
                *reinterpret_cast<unsigned int*>(&sst[par ^ 1][32 * wv + 2 * l]) = pk;
            }
            p0 = np0; p1 = np1;
            par ^= 1;
            BAR_LGKM();   // Δa: lgkm-only step barrier
        }
    }

    if (q == 0) {
        out[r * H_N + 32 * wv + l]      = y0;
        out[r * H_N + 32 * wv + 16 + l] = y1;
    }
}

extern "C" void kernel_launch(void* const* d_in, const int* in_sizes, int n_in,
                              void* d_out, int out_size, void* d_ws, size_t ws_size,
                              hipStream_t stream) {
    const float* x    = (const float*)d_in[0];  // [B][T][D] fp32
    const float* w    = (const float*)d_in[1];  // [D][H]    fp32
    const float* wst  = (const float*)d_in[2];  // [H][H]    fp32
    const float* bias = (const float*)d_in[3];  // [H]       fp32
    float* out = (float*)d_out;                 // [B][H]    fp32

    k_fused<<<256, 256, 0, stream>>>(x, w, wst, bias, out);
}

// Round 10
// 443.924 us; speedup vs baseline: 1.1673x; 1.1673x over previous
//
#include <hip/hip_runtime.h>

#define T_N 1024
#define H_N 128
#define CH   64
#define NCH (T_N / CH)     // 16
#define WPAD 136           // shorts per row of bf16 weight tiles
#define PPAD 68            // floats per row of pT

typedef __attribute__((ext_vector_type(8))) short bf16x8;
typedef __attribute__((ext_vector_type(4))) float f32x4;

__device__ __forceinline__ short f2bf_rne(float f) {
    union { float f; unsigned int i; } v; v.f = f;
    unsigned int r = v.i + 0x7FFFu + ((v.i >> 16) & 1u);
    return (short)(r >> 16);
}
__device__ __forceinline__ float tanh_fast(float x) {
    return 1.0f - 2.0f / (__expf(2.0f * x) + 1.0f);
}

// One block per batch row; 4 waves split the per-step matvec by column (nt pairs).
// x staged in VGPRs (plain loads stay in flight across step barriers -> no vmcnt
// drain at __syncthreads; waited once per chunk at the conversion).
__global__ __launch_bounds__(256, 1) void k_fused(const float* __restrict__ x,
                                                  const float* __restrict__ w,
                                                  const float* __restrict__ wst,
                                                  const float* __restrict__ bias,
                                                  float* __restrict__ out) {
    __shared__ __align__(16) short wT[H_N * WPAD];   // input-proj w, bf16 [n][k]
    __shared__ __align__(16) float pT[H_N * PPAD];   // proj chunk [h][t]; wsT staging at startup
    __shared__ __align__(16) short sst[2][H_N];      // state double buffer, bf16

    const int tid  = threadIdx.x;
    const int wv   = tid >> 6;       // wave: GEMM t-rows 16wv..16wv+15; step cols 32wv+l, 32wv+16+l
    const int lane = tid & 63;
    const int l = lane & 15;
    const int q = lane >> 4;
    const int r = blockIdx.x;
    const float* xrow = x + (size_t)r * T_N * H_N;
    const f32x4 zero4 = (f32x4){0.f, 0.f, 0.f, 0.f};

    // ---- VGPR staging: chunk 0's x rows for this lane (issued first, 32 VGPRs) ----
    const float* xlane = xrow + (size_t)(wv * 16 + l) * H_N + q * 8;
    float4 xst[8];   // [ks][half]: x[16wv+l][32ks+8q .. +7]
    #pragma unroll
    for (int ks = 0; ks < 4; ++ks) {
        xst[ks * 2 + 0] = *reinterpret_cast<const float4*>(xlane + ks * 32);
        xst[ks * 2 + 1] = *reinterpret_cast<const float4*>(xlane + ks * 32 + 4);
    }

    // ---- stage wst (bf16 [n][k]) through pT's memory ----
    short* wsT = reinterpret_cast<short*>(pT);
    for (int e = tid * 4; e < H_N * H_N; e += 1024) {
        int k = e >> 7, n = e & 127;
        float4 a4 = *reinterpret_cast<const float4*>(wst + e);
        wsT[(n + 0) * WPAD + k] = f2bf_rne(a4.x);
        wsT[(n + 1) * WPAD + k] = f2bf_rne(a4.y);
        wsT[(n + 2) * WPAD + k] = f2bf_rne(a4.z);
        wsT[(n + 3) * WPAD + k] = f2bf_rne(a4.w);
    }
    __syncthreads();

    bf16x8 wf[2][4];   // state-W B-frags for this wave's nt pair
    #pragma unroll
    for (int b = 0; b < 2; ++b)
        #pragma unroll
        for (int ks = 0; ks < 4; ++ks)
            wf[b][ks] = *reinterpret_cast<const bf16x8*>(
                &wsT[(16 * (2 * wv + b) + l) * WPAD + ks * 32 + q * 8]);
    __syncthreads();

    // ---- input-proj weights -> bf16 [n][k] LDS ----
    for (int e = tid * 4; e < H_N * H_N; e += 1024) {
        int k = e >> 7, n = e & 127;
        float4 a4 = *reinterpret_cast<const float4*>(w + e);
        wT[(n + 0) * WPAD + k] = f2bf_rne(a4.x);
        wT[(n + 1) * WPAD + k] = f2bf_rne(a4.y);
        wT[(n + 2) * WPAD + k] = f2bf_rne(a4.z);
        wT[(n + 3) * WPAD + k] = f2bf_rne(a4.w);
    }

    float bv[8];
    #pragma unroll
    for (int nt = 0; nt < 8; ++nt) bv[nt] = bias[nt * 16 + l];

    int par = 0;
    float y0 = 0.f, y1 = 0.f;
    const int row0 = (32 * wv + l) * PPAD;
    const int row1 = (32 * wv + 16 + l) * PPAD;

    #pragma unroll 1
    for (int c = 0; c < NCH; ++c) {
        // ---- cvt staged x -> bf16 A-frags (the only vmcnt wait, ~50K cyc after issue) ----
        bf16x8 ax[4];
        #pragma unroll
        for (int ks = 0; ks < 4; ++ks) {
            float4 u0 = xst[ks * 2 + 0];
            float4 u1 = xst[ks * 2 + 1];
            bf16x8 f;
            f[0] = f2bf_rne(u0.x); f[1] = f2bf_rne(u0.y);
            f[2] = f2bf_rne(u0.z); f[3] = f2bf_rne(u0.w);
            f[4] = f2bf_rne(u1.x); f[5] = f2bf_rne(u1.y);
            f[6] = f2bf_rne(u1.z); f[7] = f2bf_rne(u1.w);
            ax[ks] = f;
        }

        // ---- issue chunk c+1's staging loads (in flight across the whole step loop) ----
        if (c + 1 < NCH) {
            const float* pn = xlane + (size_t)(c + 1) * CH * H_N;
            #pragma unroll
            for (int ks = 0; ks < 4; ++ks) {
                xst[ks * 2 + 0] = *reinterpret_cast<const float4*>(pn + ks * 32);
                xst[ks * 2 + 1] = *reinterpret_cast<const float4*>(pn + ks * 32 + 4);
            }
        }

        __syncthreads();   // prev chunk's steps done reading pT (lgkm-only: no LDS-writing vmem pending)

        // ---- chunk GEMM: wave wv computes proj rows [c*64+16wv .. +15] ----
        #pragma unroll
        for (int nt = 0; nt < 8; ++nt) {
            f32x4 acc;
            #pragma unroll
            for (int ks = 0; ks < 4; ++ks) {
                bf16x8 bw = *reinterpret_cast<const bf16x8*>(
                    &wT[(nt * 16 + l) * WPAD + ks * 32 + q * 8]);
                acc = __builtin_amdgcn_mfma_f32_16x16x32_bf16(
                    ax[ks], bw, ks == 0 ? zero4 : acc, 0, 0, 0);
            }
            f32x4 o = (f32x4){acc[0] + bv[nt], acc[1] + bv[nt],
                              acc[2] + bv[nt], acc[3] + bv[nt]};
            *reinterpret_cast<f32x4*>(&pT[(nt * 16 + l) * PPAD + wv * 16 + q * 4]) = o;
        }

        __syncthreads();   // pT ready

        int tstart = 0;
        if (c == 0) {
            if (tid < 128)
                sst[0][tid] = f2bf_rne(tanh_fast(pT[tid * PPAD + 0]));
            __syncthreads();
            tstart = 1;
            par = 0;
        }

        float p0 = pT[row0 + tstart];
        float p1 = pT[row1 + tstart];

        // ---- step loop: 1 barrier/step, depth-1 MFMA, no selects ----
        #pragma unroll 1
        for (int t = tstart; t < CH; ++t) {
            bf16x8 a[4];
            #pragma unroll
            for (int ks = 0; ks < 4; ++ks)
                a[ks] = *reinterpret_cast<const bf16x8*>(&sst[par][ks * 32 + q * 8]);

            f32x4 acc[8];
            #pragma unroll
            for (int ks = 0; ks < 4; ++ks) {
                acc[ks]     = __builtin_amdgcn_mfma_f32_16x16x32_bf16(a[ks], wf[0][ks], zero4, 0, 0, 0);
                acc[4 + ks] = __builtin_amdgcn_mfma_f32_16x16x32_bf16(a[ks], wf[1][ks], zero4, 0, 0, 0);
            }

            int tn = (t + 1 < CH) ? t + 1 : t;
            float np0 = pT[row0 + tn];
            float np1 = pT[row1 + tn];

            float z0 = p0 + ((acc[0][0] + acc[1][0]) + (acc[2][0] + acc[3][0]));
            float z1 = p1 + ((acc[4][0] + acc[5][0]) + (acc[6][0] + acc[7][0]));
            y0 = tanh_fast(z0);
            y1 = tanh_fast(z1);
            sst[par ^ 1][32 * wv + l]      = f2bf_rne(y0);
            sst[par ^ 1][32 * wv + 16 + l] = f2bf_rne(y1);
            p0 = np0; p1 = np1;
            par ^= 1;
            __syncthreads();   // y_t visible to all waves (lgkm-only drain)
        }
    }

    if (q == 0) {
        out[r * H_N + 32 * wv + l]      = y0;
        out[r * H_N + 32 * wv + 16 + l] = y1;
    }
}

extern "C" void kernel_launch(void* const* d_in, const int* in_sizes, int n_in,
                              void* d_out, int out_size, void* d_ws, size_t ws_size,
                              hipStream_t stream) {
    const float* x    = (const float*)d_in[0];  // [B][T][D] fp32
    const float* w    = (const float*)d_in[1];  // [D][H]    fp32
    const float* wst  = (const float*)d_in[2];  // [H][H]    fp32
    const float* bias = (const float*)d_in[3];  // [H]       fp32
    float* out = (float*)d_out;                 // [B][H]    fp32

    k_fused<<<256, 256, 0, stream>>>(x, w, wst, bias, out);
}